// Round 8
// baseline (1150.483 us; speedup 1.0000x reference)
//
#include <hip/hip_runtime.h>
#include <math.h>

// Problem constants
#define BATCH 32
#define TLEN  4096
#define DDIM  512
#define BM    64      // rows per tile
#define BLOCK 512     // 8 waves; wave w owns output cols [64w, 64w+64)
#define NT    8       // tiles per persistent block; grid = 2048/NT = 256
// r14: T14 stage-hiding executed within register constraints. r10 failed
// (64 stage regs atop 128 accums -> spill); r13 failed (128 accums alone
// -> spill at the 128 arch-VGPR half of the unified file). Constraints now
// hard: accums <= 64 regs, transient working set <= ~100. Design: persistent
// blocks (grid=256), double-buffered h in LDS (2x64KB = r13's proven 128KB),
// stage of tile t+1 spread across BOTH GEMM k-loops (loads iters 0-7,
// writes iters 8-15, into hb[cur^1]) -> peak 8 float4 = 32 extra regs.
// u overwrites hb[cur] after barrier B (r9 trick); epilogue h re-read from
// global (L2-warm, r9-proven). Serial stage phase per tile: eliminated.

typedef __attribute__((ext_vector_type(8)))  short bf16x8;   // MFMA A/B frag
typedef __attribute__((ext_vector_type(16))) float f32x16;   // MFMA C/D frag (32x32)
typedef __attribute__((ext_vector_type(4)))  short s16x4;    // 8B LDS store

__device__ __forceinline__ short f32_to_bf16_rne(float f) {
    union { float f; unsigned int u; } v; v.f = f;
    unsigned int r = (v.u + 0x7FFFu + ((v.u >> 16) & 1u)) >> 16;
    return (short)r;
}
__device__ __forceinline__ float fast_tanh(float x) {
    x = fminf(fmaxf(x, -15.f), 15.f);
    float t = __expf(2.0f * x);
    return (t - 1.0f) / (t + 1.0f);
}

// XOR swizzle on 16B (8-short) granules. Measured 0 bank conflicts (r2-r13).
__device__ __forceinline__ int lds_idx(int r, int c) {
    int g = (c >> 3) ^ (r & 31);
    return r * DDIM + (g << 3) + (c & 7);
}

// --- kernel 1: W fp32 -> bf16 packed into MFMA-fragment order; zero l/g ------
// Element (e, d): E=e>>5, r=e&31, C=d>>4, half=(d>>3)&1, j=d&7
//   packed[ ((E*32 + C)*64 + half*32 + r)*8 + j ]
// Kernel-side (lane l): tile (E,C) base + l*8 supplies
//   W[E*32 + (l&31)][C*16 + 8*(l>>5) + j]  == MFMA fragment element.
__global__ void prep_kernel(const float* __restrict__ W1, const float* __restrict__ W2,
                            short* __restrict__ W1pk, short* __restrict__ W2pk,
                            float* __restrict__ lbuf, float* __restrict__ gbuf) {
    int i = blockIdx.x * blockDim.x + threadIdx.x;   // 0 .. 32767
    int e  = i >> 6;                 // source row
    int d0 = (i & 63) << 3;          // source col of this 8-run
    int E = e >> 5, r = e & 31, C = d0 >> 4, half = (d0 >> 3) & 1;
    size_t src = (size_t)e * DDIM + d0;
    size_t dst = ((size_t)(E * 32 + C) * 64 + half * 32 + r) * 8;
    bf16x8 p1, p2;
    #pragma unroll
    for (int j = 0; j < 8; ++j) {
        p1[j] = f32_to_bf16_rne(W1[src + j]);
        p2[j] = f32_to_bf16_rne(W2[src + j]);
    }
    *(bf16x8*)&W1pk[dst] = p1;
    *(bf16x8*)&W2pk[dst] = p2;
    if (i < BATCH * DDIM) { lbuf[i] = 0.f; gbuf[i] = 0.f; }
}

// --- kernel 2: persistent fused u=tanh(hW1^T+b1); s=uW2^T; accumulate l,g ----
__global__ __launch_bounds__(BLOCK, 2)
void main_kernel(const float* __restrict__ h,
                 const short* __restrict__ W1pk,
                 const float* __restrict__ b1,
                 const short* __restrict__ W2pk,
                 float* __restrict__ lbuf, float* __restrict__ gbuf) {
    __shared__ __align__(16) short hb[2][BM * DDIM];   // 2 x 64KB double buffer

    const int tid  = threadIdx.x;
    const int wave = tid >> 6;
    const int lane = tid & 63;
    const int l32  = lane & 31;
    const int h5   = lane >> 5;       // 0/1
    const int e0   = wave * 64;       // this wave's 64-col slice (both GEMMs)
    const int tile0 = blockIdx.x * NT;
    const int b     = (tile0 * BM) / TLEN;   // block = 512 rows, 512 | 4096

    const short* W1p = W1pk + (size_t)(e0 >> 5) * (32 * 512) + lane * 8;
    const short* W2p = W2pk + (size_t)(e0 >> 5) * (32 * 512) + lane * 8;

    // ---- prologue: stage tile 0 into hb[0] (once per block) ----
    {
        const float4* hp = (const float4*)(h + (size_t)tile0 * BM * DDIM);
        #pragma unroll
        for (int i = 0; i < 16; ++i) {
            int idx  = tid + i * BLOCK;
            float4 v = hp[idx];
            int flat = idx * 4;
            int r = flat >> 9;
            int c = flat & (DDIM - 1);
            s16x4 p;
            p.x = f32_to_bf16_rne(v.x); p.y = f32_to_bf16_rne(v.y);
            p.z = f32_to_bf16_rne(v.z); p.w = f32_to_bf16_rne(v.w);
            *(s16x4*)&hb[0][lds_idx(r, c)] = p;
        }
    }

    for (int t = 0; t < NT; ++t) {
        const int cur  = t & 1;
        const int row0 = (tile0 + t) * BM;
        const bool pf  = (t + 1 < NT);
        const float4* hpn = (const float4*)(h + (size_t)(row0 + BM) * DDIM);
        short*       hnx = hb[cur ^ 1];
        const short* hcu = hb[cur];

        __syncthreads();   // A: hb[cur] fully staged; prior readers of hnx done

        // ====== GEMM1 (swapped): C[e][t] = sum_d W1[e][d]*h[t][d] ======
        // + stage first half of h(t+1): loads iters 0-7, writes iters 8-15
        f32x16 acc[2][2];                 // [eb][tb]
        #pragma unroll
        for (int i = 0; i < 2; ++i)
            #pragma unroll
            for (int j = 0; j < 2; ++j)
                #pragma unroll
                for (int r = 0; r < 16; ++r) acc[i][j][r] = 0.f;

        bf16x8 wc[2][2], wn[2][2];        // [eb][ks], 1-iter prefetch
        #pragma unroll
        for (int eb = 0; eb < 2; ++eb)
            #pragma unroll
            for (int ks = 0; ks < 2; ++ks)
                wc[eb][ks] = *(const bf16x8*)(W1p + (eb * 32 + ks) * 512);

        float4 stg[8];
        #pragma unroll
        for (int i = 0; i < 16; ++i) {
            const int k0 = i * 32;
            bf16x8 hf[2][2];              // [tb][ks]
            #pragma unroll
            for (int tb = 0; tb < 2; ++tb)
                #pragma unroll
                for (int ks = 0; ks < 2; ++ks)
                    hf[tb][ks] = *(const bf16x8*)&hcu[lds_idx(tb * 32 + l32,
                                                              k0 + ks * 16 + 8 * h5)];
            if (i < 15) {
                #pragma unroll
                for (int eb = 0; eb < 2; ++eb)
                    #pragma unroll
                    for (int ks = 0; ks < 2; ++ks)
                        wn[eb][ks] = *(const bf16x8*)(W1p + (eb * 32 + 2 * (i + 1) + ks) * 512);
            }
            if (pf) {
                if (i < 8) {
                    stg[i] = hpn[tid + i * BLOCK];
                } else {
                    const int j = i - 8;
                    int idx  = tid + j * BLOCK;
                    int flat = idx * 4;
                    int r = flat >> 9;
                    int c = flat & (DDIM - 1);
                    s16x4 p;
                    p.x = f32_to_bf16_rne(stg[j].x); p.y = f32_to_bf16_rne(stg[j].y);
                    p.z = f32_to_bf16_rne(stg[j].z); p.w = f32_to_bf16_rne(stg[j].w);
                    *(s16x4*)&hnx[lds_idx(r, c)] = p;
                }
            }
            #pragma unroll
            for (int eb = 0; eb < 2; ++eb)
                #pragma unroll
                for (int tb = 0; tb < 2; ++tb)
                    #pragma unroll
                    for (int ks = 0; ks < 2; ++ks)
                        acc[eb][tb] = __builtin_amdgcn_mfma_f32_32x32x16_bf16(
                            wc[eb][ks], hf[tb][ks], acc[eb][tb], 0, 0, 0);
            #pragma unroll
            for (int eb = 0; eb < 2; ++eb)
                #pragma unroll
                for (int ks = 0; ks < 2; ++ks) wc[eb][ks] = wn[eb][ks];
        }

        // issue GEMM2's first W2 frags: latency hides under tanh+write+bars
        bf16x8 w2c[2][2], w2n[2][2];      // [cb][ks]
        #pragma unroll
        for (int cb = 0; cb < 2; ++cb)
            #pragma unroll
            for (int ks = 0; ks < 2; ++ks)
                w2c[cb][ks] = *(const bf16x8*)(W2p + (cb * 32 + ks) * 512);

        // bias + tanh. C/D: col(t)=lane&31, row(e)=(r&3)+8*(r>>2)+4*h5 (+32*eb)
        #pragma unroll
        for (int eb = 0; eb < 2; ++eb) {
            float4 bv[4];
            #pragma unroll
            for (int q = 0; q < 4; ++q)
                bv[q] = *(const float4*)&b1[e0 + 32 * eb + 4 * h5 + 8 * q];
            #pragma unroll
            for (int tb = 0; tb < 2; ++tb)
                #pragma unroll
                for (int r = 0; r < 16; ++r)
                    acc[eb][tb][r] = fast_tanh(acc[eb][tb][r] + bv[r >> 2][r & 3]);
        }

        __syncthreads();   // B: all reads of hcu (h) done; safe to overwrite

        // write u^T frags as u[t][e] into hcu: lane owns fixed t -> b64 stores
        #pragma unroll
        for (int eb = 0; eb < 2; ++eb)
            #pragma unroll
            for (int tb = 0; tb < 2; ++tb) {
                int tt = tb * 32 + l32;
                #pragma unroll
                for (int q = 0; q < 4; ++q) {
                    int e = e0 + 32 * eb + 4 * h5 + 8 * q;
                    s16x4 p;
                    p.x = f32_to_bf16_rne(acc[eb][tb][4 * q + 0]);
                    p.y = f32_to_bf16_rne(acc[eb][tb][4 * q + 1]);
                    p.z = f32_to_bf16_rne(acc[eb][tb][4 * q + 2]);
                    p.w = f32_to_bf16_rne(acc[eb][tb][4 * q + 3]);
                    *(s16x4*)&((short*)hcu)[lds_idx(tt, e)] = p;
                }
            }
        __syncthreads();   // C: u visible

        // ====== GEMM2 (normal): s[t][e2] = sum_e u[t][e]*W2[e2][e] ======
        // + stage second half of h(t+1): loads iters 0-7, writes iters 8-15
        f32x16 acc2[2][2];                // [tb][cb]
        #pragma unroll
        for (int i = 0; i < 2; ++i)
            #pragma unroll
            for (int j = 0; j < 2; ++j)
                #pragma unroll
                for (int r = 0; r < 16; ++r) acc2[i][j][r] = 0.f;

        #pragma unroll
        for (int i = 0; i < 16; ++i) {
            const int k0 = i * 32;
            bf16x8 uf[2][2];              // [tb][ks]
            #pragma unroll
            for (int tb = 0; tb < 2; ++tb)
                #pragma unroll
                for (int ks = 0; ks < 2; ++ks)
                    uf[tb][ks] = *(const bf16x8*)&hcu[lds_idx(tb * 32 + l32,
                                                              k0 + ks * 16 + 8 * h5)];
            if (i < 15) {
                #pragma unroll
                for (int cb = 0; cb < 2; ++cb)
                    #pragma unroll
                    for (int ks = 0; ks < 2; ++ks)
                        w2n[cb][ks] = *(const bf16x8*)(W2p + (cb * 32 + 2 * (i + 1) + ks) * 512);
            }
            if (pf) {
                if (i < 8) {
                    stg[i] = hpn[tid + (i + 8) * BLOCK];
                } else {
                    const int j = i - 8;
                    int idx  = tid + (j + 8) * BLOCK;
                    int flat = idx * 4;
                    int r = flat >> 9;
                    int c = flat & (DDIM - 1);
                    s16x4 p;
                    p.x = f32_to_bf16_rne(stg[j].x); p.y = f32_to_bf16_rne(stg[j].y);
                    p.z = f32_to_bf16_rne(stg[j].z); p.w = f32_to_bf16_rne(stg[j].w);
                    *(s16x4*)&hnx[lds_idx(r, c)] = p;
                }
            }
            #pragma unroll
            for (int tb = 0; tb < 2; ++tb)
                #pragma unroll
                for (int cb = 0; cb < 2; ++cb)
                    #pragma unroll
                    for (int ks = 0; ks < 2; ++ks)
                        acc2[tb][cb] = __builtin_amdgcn_mfma_f32_32x32x16_bf16(
                            uf[tb][ks], w2c[cb][ks], acc2[tb][cb], 0, 0, 0);
            #pragma unroll
            for (int cb = 0; cb < 2; ++cb)
                #pragma unroll
                for (int ks = 0; ks < 2; ++ks) w2c[cb][ks] = w2n[cb][ks];
        }

        // epilogue: e = exp(s); l += e; g += e*h (h re-read global, L2-warm;
        // lanes of each half read 128B contiguous per row: coalesced).
        #pragma unroll
        for (int cb = 0; cb < 2; ++cb) {
            const int e2 = e0 + 32 * cb + l32;
            const float* hp2 = h + (size_t)row0 * DDIM + e2;
            float lsum = 0.f, gsum = 0.f;
            #pragma unroll
            for (int tb = 0; tb < 2; ++tb)
                #pragma unroll
                for (int r = 0; r < 16; ++r) {
                    int tt = tb * 32 + 4 * h5 + (r & 3) + 8 * (r >> 2);
                    float ev = __expf(acc2[tb][cb][r]);   // |s| small: no max-sub
                    lsum += ev;
                    gsum += ev * hp2[(size_t)tt * DDIM];
                }
            lsum += __shfl_xor(lsum, 32);
            gsum += __shfl_xor(gsum, 32);
            if (h5 == 0) {
                atomicAdd(&lbuf[b * DDIM + e2], lsum);
                atomicAdd(&gbuf[b * DDIM + e2], gsum);
            }
        }
    }
}

// --- kernel 3: out[d] = sum_b g[b,d] / l[b,d] --------------------------------
__global__ void finish_kernel(const float* __restrict__ lbuf,
                              const float* __restrict__ gbuf,
                              float* __restrict__ out) {
    int d = blockIdx.x * blockDim.x + threadIdx.x;   // 0..511
    float s = 0.f;
    #pragma unroll
    for (int b = 0; b < BATCH; ++b)
        s += gbuf[b * DDIM + d] / lbuf[b * DDIM + d];
    out[d] = s;
}

extern "C" void kernel_launch(void* const* d_in, const int* in_sizes, int n_in,
                              void* d_out, int out_size, void* d_ws, size_t ws_size,
                              hipStream_t stream) {
    const float* h  = (const float*)d_in[0];
    const float* W1 = (const float*)d_in[1];
    const float* b1 = (const float*)d_in[2];
    const float* W2 = (const float*)d_in[3];
    float* out = (float*)d_out;

    char* ws = (char*)d_ws;
    short* W1pk = (short*)ws;                             // 512 KB (packed)
    short* W2pk = (short*)(ws + 512 * 1024);              // 512 KB (packed)
    float* lbuf = (float*)(ws + 1024 * 1024);             // 64 KB
    float* gbuf = (float*)(ws + 1024 * 1024 + 64 * 1024); // 64 KB

    prep_kernel<<<128, 256, 0, stream>>>(W1, W2, W1pk, W2pk, lbuf, gbuf);
    main_kernel<<<(BATCH * TLEN) / (BM * NT), BLOCK, 0, stream>>>(h, W1pk, b1, W2pk, lbuf, gbuf);
    finish_kernel<<<2, 256, 0, stream>>>(lbuf, gbuf, out);
}

// Round 9
// 589.163 us; speedup vs baseline: 1.9527x; 1.9527x over previous
//
#include <hip/hip_runtime.h>
#include <math.h>

// Problem constants
#define BATCH 32
#define TLEN  4096
#define DDIM  512
#define BM    128     // rows per block (128 KB LDS tile)
#define BLOCK 1024    // 16 waves; wave w owns output cols [32w, 32w+32)
// r15: geometry change at r9's register shape. Hard lesson r10/r12/r13/r14:
// only the {64 accum + ~30 transient} shape avoids spills. New split: 16
// waves x 32 e-cols (was 8 x 64). Per wave: acc f32x16[4] = 64 regs (same),
// W loads 2/iter (was 4) -> W L2 traffic per row HALVES (1MB per 128 rows);
// waves/SIMD doubles to 4 (TLP up, traffic down -- r11 showed TLP alone is
// cancelled when traffic doubles); barriers per row halve. Same verified
// stage/u-write/epilogue code with eb/cb loops collapsed to the 32-col slice.

typedef __attribute__((ext_vector_type(8)))  short bf16x8;   // MFMA A/B frag
typedef __attribute__((ext_vector_type(16))) float f32x16;   // MFMA C/D frag (32x32)
typedef __attribute__((ext_vector_type(4)))  short s16x4;    // 8B LDS store

__device__ __forceinline__ short f32_to_bf16_rne(float f) {
    union { float f; unsigned int u; } v; v.f = f;
    unsigned int r = (v.u + 0x7FFFu + ((v.u >> 16) & 1u)) >> 16;
    return (short)r;
}
__device__ __forceinline__ float fast_tanh(float x) {
    x = fminf(fmaxf(x, -15.f), 15.f);
    float t = __expf(2.0f * x);
    return (t - 1.0f) / (t + 1.0f);
}

// XOR swizzle on 16B (8-short) granules (r2-r14 verified bijection).
__device__ __forceinline__ int lds_idx(int r, int c) {
    int g = (c >> 3) ^ (r & 31);
    return r * DDIM + (g << 3) + (c & 7);
}

// --- kernel 1: W fp32 -> bf16 packed into MFMA-fragment order; zero l/g ------
// Element (e, d): E=e>>5, r=e&31, C=d>>4, half=(d>>3)&1, j=d&7
//   packed[ ((E*32 + C)*64 + half*32 + r)*8 + j ]
// Kernel-side (lane l): tile (E,C) base + l*8 supplies
//   W[E*32 + (l&31)][C*16 + 8*(l>>5) + j]  == MFMA fragment element.
__global__ void prep_kernel(const float* __restrict__ W1, const float* __restrict__ W2,
                            short* __restrict__ W1pk, short* __restrict__ W2pk,
                            float* __restrict__ lbuf, float* __restrict__ gbuf) {
    int i = blockIdx.x * blockDim.x + threadIdx.x;   // 0 .. 32767
    int e  = i >> 6;                 // source row
    int d0 = (i & 63) << 3;          // source col of this 8-run
    int E = e >> 5, r = e & 31, C = d0 >> 4, half = (d0 >> 3) & 1;
    size_t src = (size_t)e * DDIM + d0;
    size_t dst = ((size_t)(E * 32 + C) * 64 + half * 32 + r) * 8;
    bf16x8 p1, p2;
    #pragma unroll
    for (int j = 0; j < 8; ++j) {
        p1[j] = f32_to_bf16_rne(W1[src + j]);
        p2[j] = f32_to_bf16_rne(W2[src + j]);
    }
    *(bf16x8*)&W1pk[dst] = p1;
    *(bf16x8*)&W2pk[dst] = p2;
    if (i < BATCH * DDIM) { lbuf[i] = 0.f; gbuf[i] = 0.f; }
}

// --- kernel 2: fused u=tanh(hW1^T+b1); s=uW2^T; accumulate l,g ---------------
__global__ __launch_bounds__(BLOCK, 4)   // 16 waves/block -> 4 waves/EU
void main_kernel(const float* __restrict__ h,
                 const short* __restrict__ W1pk,
                 const float* __restrict__ b1,
                 const short* __restrict__ W2pk,
                 float* __restrict__ lbuf, float* __restrict__ gbuf) {
    __shared__ __align__(16) short sh[BM * DDIM];   // 128 KB: h tile, then u

    const int tid  = threadIdx.x;
    const int row0 = blockIdx.x * BM;
    const int b    = row0 / TLEN;       // BM divides TLEN: no batch straddle

    // ---- stage: global fp32 h -> LDS bf16 (coalesced float4 loads) ----
    {
        const float4* hp = (const float4*)(h + (size_t)row0 * DDIM);
        #pragma unroll
        for (int i = 0; i < (BM * DDIM / 4) / BLOCK; ++i) {   // 16 iters
            int idx  = tid + i * BLOCK;          // float4 index
            float4 v = hp[idx];
            int flat = idx * 4;
            int r = flat >> 9;                   // /512 -> 0..127
            int c = flat & (DDIM - 1);
            s16x4 p;
            p.x = f32_to_bf16_rne(v.x); p.y = f32_to_bf16_rne(v.y);
            p.z = f32_to_bf16_rne(v.z); p.w = f32_to_bf16_rne(v.w);
            *(s16x4*)&sh[lds_idx(r, c)] = p;
        }
    }
    __syncthreads();

    const int wave = tid >> 6;
    const int lane = tid & 63;
    const int l32  = lane & 31;
    const int h5   = lane >> 5;       // 0/1
    const int e0   = wave * 32;       // this wave's 32-col slice (both GEMMs)

    // ========== GEMM1 (swapped): C[e][t] = sum_d W1[e][d] * h[t][d] ==========
    // A-frag = W1 packed (coalesced: lane*16B), B-frag = h^T from LDS.
    f32x16 acc[4];                    // [tb] -- 64 accumulator regs (r9 shape)
    #pragma unroll
    for (int j = 0; j < 4; ++j)
        #pragma unroll
        for (int r = 0; r < 16; ++r) acc[j][r] = 0.f;

    const short* W1p = W1pk + (size_t)wave * (32 * 512) + lane * 8;
    bf16x8 wc[2], wn[2];              // [ks], 1-iter prefetch
    #pragma unroll
    for (int ks = 0; ks < 2; ++ks)
        wc[ks] = *(const bf16x8*)(W1p + ks * 512);

    #pragma unroll
    for (int i = 0; i < 16; ++i) {
        const int k0 = i * 32;
        bf16x8 hf[4][2];              // [tb][ks]
        #pragma unroll
        for (int tb = 0; tb < 4; ++tb)
            #pragma unroll
            for (int ks = 0; ks < 2; ++ks)
                hf[tb][ks] = *(const bf16x8*)&sh[lds_idx(tb * 32 + l32,
                                                         k0 + ks * 16 + 8 * h5)];
        if (i < 15) {                 // prefetch next k-chunk
            #pragma unroll
            for (int ks = 0; ks < 2; ++ks)
                wn[ks] = *(const bf16x8*)(W1p + (2 * (i + 1) + ks) * 512);
        }
        #pragma unroll
        for (int tb = 0; tb < 4; ++tb)
            #pragma unroll
            for (int ks = 0; ks < 2; ++ks)
                acc[tb] = __builtin_amdgcn_mfma_f32_32x32x16_bf16(
                    wc[ks], hf[tb][ks], acc[tb], 0, 0, 0);
        #pragma unroll
        for (int ks = 0; ks < 2; ++ks) wc[ks] = wn[ks];
    }

    // issue GEMM2's first W2 frags: L2 latency hides under tanh+write+bars
    const short* W2p = W2pk + (size_t)wave * (32 * 512) + lane * 8;
    bf16x8 w2c[2], w2n[2];            // [ks]
    #pragma unroll
    for (int ks = 0; ks < 2; ++ks)
        w2c[ks] = *(const bf16x8*)(W2p + ks * 512);

    // bias + tanh. C/D map: col(t)=lane&31, row(e)=(r&3)+8*(r>>2)+4*h5
    {
        float4 bv[4];
        #pragma unroll
        for (int q = 0; q < 4; ++q)
            bv[q] = *(const float4*)&b1[e0 + 4 * h5 + 8 * q];
        #pragma unroll
        for (int tb = 0; tb < 4; ++tb)
            #pragma unroll
            for (int r = 0; r < 16; ++r)
                acc[tb][r] = fast_tanh(acc[tb][r] + bv[r >> 2][r & 3]);
    }

    __syncthreads();   // all waves done reading h tile; safe to overwrite with u

    // write u^T frags as u[t][e]: lane owns fixed t, 4-consec-e runs -> b64
    #pragma unroll
    for (int tb = 0; tb < 4; ++tb) {
        int tt = tb * 32 + l32;
        #pragma unroll
        for (int q = 0; q < 4; ++q) {
            int e = e0 + 4 * h5 + 8 * q;
            s16x4 p;
            p.x = f32_to_bf16_rne(acc[tb][4 * q + 0]);
            p.y = f32_to_bf16_rne(acc[tb][4 * q + 1]);
            p.z = f32_to_bf16_rne(acc[tb][4 * q + 2]);
            p.w = f32_to_bf16_rne(acc[tb][4 * q + 3]);
            *(s16x4*)&sh[lds_idx(tt, e)] = p;
        }
    }
    __syncthreads();

    // ========== GEMM2 (normal): s[t][e2] = sum_e u[t][e] * W2[e2][e] =========
    f32x16 acc2[4];                   // [tb]
    #pragma unroll
    for (int j = 0; j < 4; ++j)
        #pragma unroll
        for (int r = 0; r < 16; ++r) acc2[j][r] = 0.f;

    #pragma unroll
    for (int i = 0; i < 16; ++i) {
        const int k0 = i * 32;
        bf16x8 uf[4][2];              // [tb][ks]
        #pragma unroll
        for (int tb = 0; tb < 4; ++tb)
            #pragma unroll
            for (int ks = 0; ks < 2; ++ks)
                uf[tb][ks] = *(const bf16x8*)&sh[lds_idx(tb * 32 + l32,
                                                         k0 + ks * 16 + 8 * h5)];
        if (i < 15) {                 // prefetch next k-chunk
            #pragma unroll
            for (int ks = 0; ks < 2; ++ks)
                w2n[ks] = *(const bf16x8*)(W2p + (2 * (i + 1) + ks) * 512);
        }
        #pragma unroll
        for (int tb = 0; tb < 4; ++tb)
            #pragma unroll
            for (int ks = 0; ks < 2; ++ks)
                acc2[tb] = __builtin_amdgcn_mfma_f32_32x32x16_bf16(
                    uf[tb][ks], w2c[ks], acc2[tb], 0, 0, 0);
        #pragma unroll
        for (int ks = 0; ks < 2; ++ks) w2c[ks] = w2n[ks];
    }

    // epilogue: e = exp(s); l += e; g += e*h (h re-read global, L2-warm;
    // lanes 0-31 of each half read 128B contiguous per row: coalesced).
    {
        const int e2 = e0 + l32;
        const float* hp2 = h + (size_t)row0 * DDIM + e2;
        float lsum = 0.f, gsum = 0.f;
        #pragma unroll
        for (int tb = 0; tb < 4; ++tb)
            #pragma unroll
            for (int r = 0; r < 16; ++r) {
                int tt = tb * 32 + 4 * h5 + (r & 3) + 8 * (r >> 2);
                float ev = __expf(acc2[tb][r]);   // |s| small: no max-sub
                lsum += ev;
                gsum += ev * hp2[(size_t)tt * DDIM];
            }
        lsum += __shfl_xor(lsum, 32);
        gsum += __shfl_xor(gsum, 32);
        if (h5 == 0) {
            atomicAdd(&lbuf[b * DDIM + e2], lsum);
            atomicAdd(&gbuf[b * DDIM + e2], gsum);
        }
    }
}

// --- kernel 3: out[d] = sum_b g[b,d] / l[b,d] --------------------------------
__global__ void finish_kernel(const float* __restrict__ lbuf,
                              const float* __restrict__ gbuf,
                              float* __restrict__ out) {
    int d = blockIdx.x * blockDim.x + threadIdx.x;   // 0..511
    float s = 0.f;
    #pragma unroll
    for (int b = 0; b < BATCH; ++b)
        s += gbuf[b * DDIM + d] / lbuf[b * DDIM + d];
    out[d] = s;
}

extern "C" void kernel_launch(void* const* d_in, const int* in_sizes, int n_in,
                              void* d_out, int out_size, void* d_ws, size_t ws_size,
                              hipStream_t stream) {
    const float* h  = (const float*)d_in[0];
    const float* W1 = (const float*)d_in[1];
    const float* b1 = (const float*)d_in[2];
    const float* W2 = (const float*)d_in[3];
    float* out = (float*)d_out;

    char* ws = (char*)d_ws;
    short* W1pk = (short*)ws;                             // 512 KB (packed)
    short* W2pk = (short*)(ws + 512 * 1024);              // 512 KB (packed)
    float* lbuf = (float*)(ws + 1024 * 1024);             // 64 KB
    float* gbuf = (float*)(ws + 1024 * 1024 + 64 * 1024); // 64 KB

    prep_kernel<<<128, 256, 0, stream>>>(W1, W2, W1pk, W2pk, lbuf, gbuf);
    main_kernel<<<(BATCH * TLEN) / BM, BLOCK, 0, stream>>>(h, W1pk, b1, W2pk, lbuf, gbuf);
    finish_kernel<<<2, 256, 0, stream>>>(lbuf, gbuf, out);
}